// Round 3
// baseline (326.601 us; speedup 1.0000x reference)
//
#include <hip/hip_runtime.h>
#include <hip/hip_cooperative_groups.h>

namespace cg = cooperative_groups;

#define N_IMG 8
#define CIN   64
#define H     112
#define W     112
#define P     (H * W)          // 12544
#define PG    (P / 4)          // 3136 float4 pixel-groups
#define D     576              // CIN * 3 * 3
#define COUT  64
#define MEM   1025             // memo table size
#define SENT  P                // sentinel for "no patch yet"
#define GRID  512              // 2 blocks/CU on 256 CUs: co-residency safe
#define BLK   256

// Single fused cooperative kernel: prep+chansum | bins | rep | scatter
__global__ __launch_bounds__(BLK) void fused_kernel(
    const float* __restrict__ fmap, const float* __restrict__ weight,
    const float* __restrict__ bias, float* __restrict__ out,
    double* __restrict__ T, int* __restrict__ bins, int* __restrict__ first,
    float* __restrict__ wT, float* __restrict__ rep) {
  cg::grid_group grid = cg::this_grid();
  __shared__ union SharedU {
    int lfirst[MEM];                                   // phase 1 (4100 B)
    struct { float patch[D]; float partial[4][COUT]; } rp;  // phase 2 (3328 B)
  } sh;

  const int t   = threadIdx.x;
  const int gid = blockIdx.x;
  const int tid = gid * BLK + t;

  // ---- Phase 0: prep (first init + weight transpose) + channel sums ------
  if (tid < N_IMG * MEM) first[tid] = SENT;
  if (tid < D * COUT) {
    int d = tid / COUT, co = tid - d * COUT;
    wT[tid] = weight[co * D + d];
  }
  // channel sum: unit u = task*4 + seg; task = (n, pixel-group); seg = 16-chan quarter
  if (tid < N_IMG * PG * 4) {
    int task = tid >> 2, seg = tid & 3;
    int n = task / PG;
    int pg = task - n * PG;
    const float* base = fmap + ((size_t)n * CIN) * P + pg * 4;
    double s0 = 0.0, s1 = 0.0, s2 = 0.0, s3 = 0.0;
    int c0 = seg * 16;
    #pragma unroll
    for (int c = c0; c < c0 + 16; ++c) {
      float4 v = *reinterpret_cast<const float4*>(base + (size_t)c * P);
      s0 += (double)v.x; s1 += (double)v.y; s2 += (double)v.z; s3 += (double)v.w;
    }
    // reduce across the 4 seg-lanes (consecutive lanes in the wave)
    s0 += __shfl_xor(s0, 1); s1 += __shfl_xor(s1, 1);
    s2 += __shfl_xor(s2, 1); s3 += __shfl_xor(s3, 1);
    s0 += __shfl_xor(s0, 2); s1 += __shfl_xor(s1, 2);
    s2 += __shfl_xor(s2, 2); s3 += __shfl_xor(s3, 2);
    if (seg == 0) {
      double4 o; o.x = s0; o.y = s1; o.z = s2; o.w = s3;
      *reinterpret_cast<double4*>(T + (size_t)n * P + pg * 4) = o;
    }
  }

  grid.sync();

  // ---- Phase 1: 3x3 box sum -> bin; LDS dedup; sparse global flush -------
  if (gid < N_IMG * 49) {                       // 49 blocks x 256 px per image
    for (int i = t; i < MEM; i += BLK) sh.lfirst[i] = SENT;
    __syncthreads();
    int n = gid / 49;
    int p = (gid % 49) * BLK + t;               // < 12544 always
    int h = p / W, w = p - h * W;
    const double* Tn = T + (size_t)n * P;
    double s = 0.0;
    #pragma unroll
    for (int dh = -1; dh <= 1; ++dh) {
      int hh = h + dh;
      if (hh < 0 || hh >= H) continue;
      #pragma unroll
      for (int dw = -1; dw <= 1; ++dw) {
        int ww = w + dw;
        if (ww < 0 || ww >= W) continue;
        s += Tn[hh * W + ww];
      }
    }
    // replicate reference f32 ops: mean = sum/576 ; v = mean*100 ; trunc
    float sf = (float)s;
    float mean = sf / 576.0f;
    float v = mean * 100.0f;
    int qv = (int)v;                            // trunc == astype(int32)
    int b = qv + 512;                           // - MIN_SUMMARY
    b = b < 0 ? 0 : (b > MEM - 1 ? MEM - 1 : b);
    bins[n * P + p] = b;
    atomicMin(&sh.lfirst[b], p);                // LDS-scope
    __syncthreads();
    for (int i = t; i < MEM; i += BLK) {
      int v2 = sh.lfirst[i];
      if (v2 != SENT) atomicMin(&first[n * MEM + i], v2);
    }
  }

  grid.sync();

  // ---- Phase 2: representative GEMM per live (n, bin) pair ---------------
  for (int pair = gid; pair < N_IMG * MEM; pair += GRID) {
    int n = pair / MEM, b = pair - n * MEM;
    int fi = first[pair];
    if (fi >= SENT) continue;                   // block-uniform
    int h = fi / W, w = fi - h * W;
    for (int d = t; d < D; d += BLK) {          // d = c*9 + kh*3 + kw
      int c = d / 9, r = d - c * 9;
      int kh = r / 3, kw = r - kh * 3;
      int hh = h + kh - 1, ww = w + kw - 1;
      float val = 0.0f;
      if (hh >= 0 && hh < H && ww >= 0 && ww < W)
        val = fmap[((size_t)(n * CIN + c)) * P + hh * W + ww];
      sh.rp.patch[d] = val;
    }
    __syncthreads();
    int co = t & 63, seg = t >> 6;              // 4 segments x 144 d-values
    float acc = 0.0f;
    int d0 = seg * 144;
    #pragma unroll 4
    for (int d = d0; d < d0 + 144; ++d)
      acc += sh.rp.patch[d] * wT[d * COUT + co];
    sh.rp.partial[seg][co] = acc;
    __syncthreads();
    if (t < COUT) {
      float total = sh.rp.partial[0][t] + sh.rp.partial[1][t] +
                    sh.rp.partial[2][t] + sh.rp.partial[3][t] + bias[t];
      rep[((size_t)pair) * COUT + t] = total;
    }
    __syncthreads();                            // protect patch/partial reuse
  }

  grid.sync();

  // ---- Phase 3: scatter out[n,co,p] = rep[n, bins[n,p], co] --------------
  const int NTASK = N_IMG * COUT * PG;          // 1,605,632
  for (int idx = tid; idx < NTASK; idx += GRID * BLK) {
    int pv = idx % PG;
    int rest = idx / PG;
    int co = rest & 63;
    int n = rest >> 6;
    int4 b4 = *reinterpret_cast<const int4*>(bins + n * P + pv * 4);
    const float* repn = rep + (size_t)n * MEM * COUT + co;
    float4 o;
    o.x = repn[(size_t)b4.x * COUT];
    o.y = repn[(size_t)b4.y * COUT];
    o.z = repn[(size_t)b4.z * COUT];
    o.w = repn[(size_t)b4.w * COUT];
    *reinterpret_cast<float4*>(out + ((size_t)n * COUT + co) * P + pv * 4) = o;
  }
}

// ---------------------------------------------------------------------------
extern "C" void kernel_launch(void* const* d_in, const int* in_sizes, int n_in,
                              void* d_out, int out_size, void* d_ws, size_t ws_size,
                              hipStream_t stream) {
  const float* fmap   = (const float*)d_in[0];
  const float* weight = (const float*)d_in[1];
  const float* bias   = (const float*)d_in[2];
  float* out = (float*)d_out;

  char* ws = (char*)d_ws;
  double* T   = (double*)(ws);                 // 8*12544*8    = 802816 B
  int*   bins = (int*)  (ws + 802816);         // 8*12544*4    = 401408 B
  int*  first = (int*)  (ws + 1204224);        // 8*1025*4     =  32800 B
  float*   wT = (float*)(ws + 1237248);        // 576*64*4     = 147456 B
  float*  rep = (float*)(ws + 1384704);        // 8*1025*64*4  = 2099200 B

  void* args[] = {(void*)&fmap, (void*)&weight, (void*)&bias, (void*)&out,
                  (void*)&T, (void*)&bins, (void*)&first, (void*)&wT, (void*)&rep};
  hipLaunchCooperativeKernel((const void*)fused_kernel, dim3(GRID), dim3(BLK),
                             args, 0, stream);
}

// Round 4
// 113.849 us; speedup vs baseline: 2.8687x; 2.8687x over previous
//
#include <hip/hip_runtime.h>

#define N_IMG 8
#define CIN   64
#define H     112
#define W     112
#define P     (H * W)          // 12544
#define PG    (P / 4)          // 3136 float4 pixel-groups
#define D     576              // CIN * 3 * 3
#define COUT  64
#define MEM   1025             // memo table size
#define RB    4                // output rows per band
#define NBAND (H / RB)         // 28
#define HALO_PIX ((RB + 2) * W)  // 672
#define OUT_PIX  (RB * W)        // 448
#define NB_BINS (N_IMG * NBAND)  // 224 band blocks
#define NB_WT   16               // weight-transpose blocks

// ---------------------------------------------------------------------------
// K1: fused per-pixel channel sum (f64) + 3x3 zero-padded box sum + quantize
//     + per-block LDS dedup + sparse global atomicMin flush.
//     Blocks 0..223: (image, row-band). Blocks 224..239: weight transpose.
__global__ __launch_bounds__(256) void fused_bins_kernel(
    const float* __restrict__ fmap, const float* __restrict__ weight,
    float* __restrict__ wT, int* __restrict__ bins,
    unsigned* __restrict__ first) {
  __shared__ double Tl[HALO_PIX];      // 5376 B: channel sums for 6 halo rows
  __shared__ int lfirst[MEM];          // 4100 B: per-block dedup table
  const int t = threadIdx.x;
  const int g = blockIdx.x;

  if (g >= NB_BINS) {
    // ---- weight transpose: wT[d*COUT+co] = weight[co*D+d], coalesced reads
    for (int i = (g - NB_BINS) * 256 + t; i < D * COUT; i += NB_WT * 256) {
      int co = i / D, d = i - co * D;
      wT[d * COUT + co] = weight[i];
    }
    return;
  }

  const int n = g / NBAND;
  const int band = g - n * NBAND;
  const int r0 = band * RB;

  for (int i = t; i < MEM; i += 256) lfirst[i] = P;   // local sentinel

  // channel sums for rows r0-1 .. r0+RB (zero for out-of-image rows)
  const float* fb = fmap + (size_t)n * CIN * P;
  for (int j = t; j < HALO_PIX; j += 256) {
    int lr = j / W, w = j - lr * W;
    int gh = r0 - 1 + lr;
    double s = 0.0;
    if (gh >= 0 && gh < H) {
      const float* pp = fb + gh * W + w;
      #pragma unroll
      for (int c = 0; c < CIN; ++c) s += (double)pp[(size_t)c * P];
    }
    Tl[j] = s;
  }
  __syncthreads();

  // 3x3 box sum -> replicate reference f32 ops -> bin -> LDS dedup
  for (int k = t; k < OUT_PIX; k += 256) {
    int orow = k / W, w = k - orow * W;
    double s = 0.0;
    #pragma unroll
    for (int dh = 0; dh < 3; ++dh) {
      const double* row = &Tl[(orow + dh) * W];
      #pragma unroll
      for (int dw = -1; dw <= 1; ++dw) {
        int ww = w + dw;
        if (ww < 0 || ww >= W) continue;
        s += row[ww];
      }
    }
    float sf = (float)s;
    float mean = sf / 576.0f;
    float v = mean * 100.0f;
    int qv = (int)v;                    // trunc toward zero == astype(int32)
    int b = qv + 512;                   // - MIN_SUMMARY
    b = b < 0 ? 0 : (b > MEM - 1 ? MEM - 1 : b);
    int p = (r0 + orow) * W + w;
    bins[n * P + p] = b;
    atomicMin(&lfirst[b], p);           // LDS-scope: fast
  }
  __syncthreads();

  // sparse flush (~20-40 live entries per block)
  for (int i = t; i < MEM; i += 256) {
    int v = lfirst[i];
    if (v != P) atomicMin(&first[n * MEM + i], (unsigned)v);
  }
}

// ---------------------------------------------------------------------------
// K2: representative GEMM per live (n, bin) pair; dead blocks exit on one read.
__global__ __launch_bounds__(256) void rep_kernel(
    const float* __restrict__ fmap, const float* __restrict__ wT,
    const float* __restrict__ bias, const unsigned* __restrict__ first,
    float* __restrict__ rep) {
  const int pair = blockIdx.x;          // n*MEM + b
  unsigned fi = first[pair];
  if (fi >= (unsigned)P) return;        // sentinel 0xFFFFFFFF or unused
  const int n = pair / MEM;
  __shared__ float patch[D];
  __shared__ float partial[4][COUT];
  const int t = threadIdx.x;
  int h = (int)fi / W, w = (int)fi - h * W;
  // gather patch: d = c*9 + kh*3 + kw (conv_general_dilated_patches order)
  for (int d = t; d < D; d += 256) {
    int c = d / 9, r = d - c * 9;
    int kh = r / 3, kw = r - kh * 3;
    int hh = h + kh - 1, ww = w + kw - 1;
    float val = 0.0f;
    if (hh >= 0 && hh < H && ww >= 0 && ww < W)
      val = fmap[((size_t)(n * CIN + c)) * P + hh * W + ww];
    patch[d] = val;
  }
  __syncthreads();
  int co = t & 63, seg = t >> 6;        // 4 segments x 144 d-values
  float acc = 0.0f;
  int d0 = seg * 144;
  #pragma unroll 4
  for (int d = d0; d < d0 + 144; ++d)
    acc += patch[d] * wT[d * COUT + co];
  partial[seg][co] = acc;
  __syncthreads();
  if (t < COUT) {
    float total = partial[0][t] + partial[1][t] + partial[2][t] + partial[3][t] + bias[t];
    rep[((size_t)pair) * COUT + t] = total;
  }
}

// ---------------------------------------------------------------------------
// K3: scatter out[n,co,p] = rep[n, bins[n,p], co], float4 writes
__global__ __launch_bounds__(256) void scatter_kernel(
    const int* __restrict__ bins, const float* __restrict__ rep,
    float* __restrict__ out) {
  int idx = blockIdx.x * 256 + threadIdx.x;          // over N*COUT*PG
  if (idx >= N_IMG * COUT * PG) return;
  int pv = idx % PG;
  int rest = idx / PG;
  int co = rest & 63;
  int n = rest >> 6;
  int4 b4 = *reinterpret_cast<const int4*>(bins + n * P + pv * 4);
  const float* repn = rep + (size_t)n * MEM * COUT + co;
  float4 o;
  o.x = repn[(size_t)b4.x * COUT];
  o.y = repn[(size_t)b4.y * COUT];
  o.z = repn[(size_t)b4.z * COUT];
  o.w = repn[(size_t)b4.w * COUT];
  *reinterpret_cast<float4*>(out + ((size_t)n * COUT + co) * P + pv * 4) = o;
}

// ---------------------------------------------------------------------------
extern "C" void kernel_launch(void* const* d_in, const int* in_sizes, int n_in,
                              void* d_out, int out_size, void* d_ws, size_t ws_size,
                              hipStream_t stream) {
  const float* fmap   = (const float*)d_in[0];
  const float* weight = (const float*)d_in[1];
  const float* bias   = (const float*)d_in[2];
  float* out = (float*)d_out;

  char* ws = (char*)d_ws;
  // workspace layout (all 64B-aligned)
  int*      bins  = (int*)     (ws);             // 8*12544*4   = 401408 B
  unsigned* first = (unsigned*)(ws + 401408);    // 8*1025*4    =  32800 B
  float*    wT    = (float*)   (ws + 434240);    // 576*64*4    = 147456 B
  float*    rep   = (float*)   (ws + 581696);    // 8*1025*64*4 = 2099200 B

  // sentinel init: 0xFFFFFFFF == "no patch yet" for unsigned atomicMin
  hipMemsetAsync(first, 0xFF, N_IMG * MEM * sizeof(unsigned), stream);

  hipLaunchKernelGGL(fused_bins_kernel, dim3(NB_BINS + NB_WT), dim3(256), 0, stream,
                     fmap, weight, wT, bins, first);
  hipLaunchKernelGGL(rep_kernel, dim3(N_IMG * MEM), dim3(256), 0, stream,
                     fmap, wT, bias, first, rep);
  hipLaunchKernelGGL(scatter_kernel, dim3((N_IMG * COUT * PG + 255) / 256), dim3(256), 0, stream,
                     bins, rep, out);
}